// Round 1
// baseline (309.507 us; speedup 1.0000x reference)
//
#include <hip/hip_runtime.h>
#include <math.h>

#define DD 64
#define CC 128
#define HH 512
#define BATCH 4096

// Transpose W3 (H, 2D) -> W3T (2D, H) so per-step column reads are contiguous.
__global__ void transpose_w3(const float* __restrict__ W3, float* __restrict__ W3T) {
    int idx = blockIdx.x * blockDim.x + threadIdx.x;   // 0 .. 2D*H-1 = 65535
    int c = idx >> 9;        // output row: 0..127
    int j = idx & 511;       // output col: 0..511
    W3T[idx] = W3[j * (2 * DD) + c];
}

__device__ __forceinline__ void load8(const float* __restrict__ p, float* r) {
    float4 a = *(const float4*)(p);
    float4 b = *(const float4*)(p + 4);
    r[0] = a.x; r[1] = a.y; r[2] = a.z; r[3] = a.w;
    r[4] = b.x; r[5] = b.y; r[6] = b.z; r[7] = b.w;
}

// One wave (64 lanes) per batch row. Lane l owns hidden units j = 8l..8l+7.
// deg(j) = (j % 63) + 1.  Incremental MADE sampling:
//   pre1 = b1 + ctx@W1[D:,:]; pre2 = b2; h2f = 0
//   step i: (a) h1 units with deg==i are final -> relu -> rank-|K_i| update of pre2
//           (b) h2 units with deg==i are final -> h2f = relu(pre2)
//           (c) out_i = <h2f, W3T[i,:]>, pres_i = <h2f, W3T[D+i,:]>  (wave reduce)
//           (d) z_i = mean + softplus(pres)*eps_i ; pre1 += z_i * W1[i,:]
// Mask-violating accumulations only touch already-captured entries -> harmless.
__global__ __launch_bounds__(256) void made_sample(
    const float* __restrict__ ctx,   // (B, C)
    const float* __restrict__ eps,   // (B, D)
    const float* __restrict__ W1,    // (D+C, H)
    const float* __restrict__ b1,    // (H)
    const float* __restrict__ W2,    // (H, H)
    const float* __restrict__ b2,    // (H)
    const float* __restrict__ b3,    // (2D)
    const float* __restrict__ W3T,   // (2D, H)
    float* __restrict__ out)         // (B, D)
{
    const int lane = threadIdx.x & 63;
    const int row  = blockIdx.x * 4 + (threadIdx.x >> 6);
    const int jbase = 8 * lane;

    int deg[8];
    #pragma unroll
    for (int u = 0; u < 8; ++u) deg[u] = (jbase + u) % 63 + 1;

    float pre1[8], pre2[8], h2f[8];
    load8(b1 + jbase, pre1);
    load8(b2 + jbase, pre2);
    #pragma unroll
    for (int u = 0; u < 8; ++u) h2f[u] = 0.f;

    // --- init: pre1 += ctx @ W1[D:, :]  (context block, unmasked) ---
    const float c0 = ctx[row * CC + lane];
    const float c1 = ctx[row * CC + 64 + lane];
    #pragma unroll 1
    for (int c = 0; c < 64; ++c) {
        float cv = __shfl(c0, c);
        float w[8]; load8(W1 + (DD + c) * HH + jbase, w);
        #pragma unroll
        for (int u = 0; u < 8; ++u) pre1[u] = fmaf(cv, w[u], pre1[u]);
    }
    #pragma unroll 1
    for (int c = 0; c < 64; ++c) {
        float cv = __shfl(c1, c);
        float w[8]; load8(W1 + (DD + 64 + c) * HH + jbase, w);
        #pragma unroll
        for (int u = 0; u < 8; ++u) pre1[u] = fmaf(cv, w[u], pre1[u]);
    }

    const float veps = eps[row * DD + lane];
    float zreg = 0.f;

    #pragma unroll 1
    for (int i = 0; i < DD; ++i) {
        // (a) capture h1 for deg==i, broadcast, rank-update pre2
        float myh1 = 0.f;
        #pragma unroll
        for (int u = 0; u < 8; ++u) myh1 = (deg[u] == i) ? pre1[u] : myh1;
        myh1 = fmaxf(myh1, 0.f);
        const int nK = (i == 0) ? 0 : ((i <= 8) ? 9 : 8);
        for (int t = 0; t < nK; ++t) {
            const int k = (i - 1) + 63 * t;           // row of W2, deg(k)==i
            const float h = __shfl(myh1, k >> 3);
            float w[8]; load8(W2 + k * HH + jbase, w);
            #pragma unroll
            for (int u = 0; u < 8; ++u) pre2[u] = fmaf(h, w[u], pre2[u]);
        }
        // (b) capture h2 for deg==i
        #pragma unroll
        for (int u = 0; u < 8; ++u)
            if (deg[u] == i) h2f[u] = fmaxf(pre2[u], 0.f);
        // (c) output columns i and D+i
        float wm[8], wp[8];
        load8(W3T + i * HH + jbase, wm);
        load8(W3T + (DD + i) * HH + jbase, wp);
        float macc = 0.f, pacc = 0.f;
        #pragma unroll
        for (int u = 0; u < 8; ++u) {
            macc = fmaf(h2f[u], wm[u], macc);
            pacc = fmaf(h2f[u], wp[u], pacc);
        }
        #pragma unroll
        for (int off = 32; off > 0; off >>= 1) {
            macc += __shfl_xor(macc, off);
            pacc += __shfl_xor(pacc, off);
        }
        const float mean = macc + b3[i];
        const float pres = pacc + b3[DD + i];
        const float sp = fmaxf(pres, 0.f) + log1pf(expf(-fabsf(pres)));
        const float epsi = __shfl(veps, i);
        const float zi = mean + sp * epsi;
        if (lane == i) zreg = zi;
        // (d) pre1 += z_i * W1[i, :]
        float w1r[8]; load8(W1 + i * HH + jbase, w1r);
        #pragma unroll
        for (int u = 0; u < 8; ++u) pre1[u] = fmaf(zi, w1r[u], pre1[u]);
    }

    out[row * DD + lane] = zreg;
}

extern "C" void kernel_launch(void* const* d_in, const int* in_sizes, int n_in,
                              void* d_out, int out_size, void* d_ws, size_t ws_size,
                              hipStream_t stream) {
    const float* ctx = (const float*)d_in[0];
    const float* eps = (const float*)d_in[1];
    const float* W1  = (const float*)d_in[2];
    const float* b1  = (const float*)d_in[3];
    const float* W2  = (const float*)d_in[4];
    const float* b2  = (const float*)d_in[5];
    const float* W3  = (const float*)d_in[6];
    const float* b3  = (const float*)d_in[7];
    float* W3T = (float*)d_ws;   // 2D*H floats = 256 KiB

    transpose_w3<<<(2 * DD * HH) / 256, 256, 0, stream>>>(W3, W3T);
    made_sample<<<BATCH / 4, 256, 0, stream>>>(ctx, eps, W1, b1, W2, b2, b3, W3T,
                                               (float*)d_out);
}

// Round 2
// 281.789 us; speedup vs baseline: 1.0984x; 1.0984x over previous
//
#include <hip/hip_runtime.h>
#include <math.h>

#define DD 64
#define CC 128
#define HH 512
#define BATCH 4096

// Transpose W3 (H, 2D) -> W3T (2D, H) so per-step column reads are contiguous.
__global__ void transpose_w3(const float* __restrict__ W3, float* __restrict__ W3T) {
    int idx = blockIdx.x * blockDim.x + threadIdx.x;   // 0 .. 2D*H-1
    int c = idx >> 9;        // output row: 0..127
    int j = idx & 511;       // output col: 0..511
    W3T[idx] = W3[j * (2 * DD) + c];
}

__device__ __forceinline__ void load8(const float* __restrict__ p, float* r) {
    float4 a = *(const float4*)(p);
    float4 b = *(const float4*)(p + 4);
    r[0] = a.x; r[1] = a.y; r[2] = a.z; r[3] = a.w;
    r[4] = b.x; r[5] = b.y; r[6] = b.z; r[7] = b.w;
}

__device__ __forceinline__ float fast_softplus(float x) {
    // softplus(x) = max(x,0) + ln(1 + e^{-|x|});  exp2f/log2f -> v_exp_f32/v_log_f32
    float t = exp2f(-fabsf(x) * 1.44269504f);
    return fmaxf(x, 0.f) + 0.69314718f * log2f(1.f + t);
}

// One wave = 2 batch rows (A,B). Lane l owns hidden units j = 8l..8l+7 for both.
// deg(j) = (j % 63) + 1. Incremental MADE sampling (see R0 derivation):
// weight loads + addressing shared across the two rows; the two rows' FMA
// chains are independent -> 2x ILP in every latency window.
// Branch-free rank update: at i==0 the selected h1 is 0 (cndmask default),
// so clamped-address rows contribute nothing; t=8 row zeroed for i>8.
__global__ __launch_bounds__(256) void made_sample(
    const float* __restrict__ ctx,   // (B, C)
    const float* __restrict__ eps,   // (B, D)
    const float* __restrict__ W1,    // (D+C, H)
    const float* __restrict__ b1,    // (H)
    const float* __restrict__ W2,    // (H, H)
    const float* __restrict__ b2,    // (H)
    const float* __restrict__ b3,    // (2D)
    const float* __restrict__ W3T,   // (2D, H)
    float* __restrict__ out)         // (B, D)
{
    const int lane  = threadIdx.x & 63;
    const int wid   = threadIdx.x >> 6;
    const int rowA  = blockIdx.x * 8 + wid * 2;
    const int rowB  = rowA + 1;
    const int jbase = 8 * lane;

    int deg[8];
    #pragma unroll
    for (int u = 0; u < 8; ++u) deg[u] = (jbase + u) % 63 + 1;

    float p1a[8], p1b[8], p2a[8], p2b[8], h2a[8], h2b[8];
    load8(b1 + jbase, p1a);
    load8(b2 + jbase, p2a);
    #pragma unroll
    for (int u = 0; u < 8; ++u) { p1b[u] = p1a[u]; p2b[u] = p2a[u]; h2a[u] = 0.f; h2b[u] = 0.f; }

    // --- init: pre1 += ctx @ W1[D:, :]  (context block, unmasked) ---
    const float a0 = ctx[rowA * CC + lane];
    const float a1 = ctx[rowA * CC + 64 + lane];
    const float c0 = ctx[rowB * CC + lane];
    const float c1 = ctx[rowB * CC + 64 + lane];
    #pragma unroll 1
    for (int c = 0; c < 64; ++c) {
        float w[8]; load8(W1 + (DD + c) * HH + jbase, w);
        float va = __shfl(a0, c), vb = __shfl(c0, c);
        #pragma unroll
        for (int u = 0; u < 8; ++u) {
            p1a[u] = fmaf(va, w[u], p1a[u]);
            p1b[u] = fmaf(vb, w[u], p1b[u]);
        }
    }
    #pragma unroll 1
    for (int c = 0; c < 64; ++c) {
        float w[8]; load8(W1 + (DD + 64 + c) * HH + jbase, w);
        float va = __shfl(a1, c), vb = __shfl(c1, c);
        #pragma unroll
        for (int u = 0; u < 8; ++u) {
            p1a[u] = fmaf(va, w[u], p1a[u]);
            p1b[u] = fmaf(vb, w[u], p1b[u]);
        }
    }

    const float epsA = eps[rowA * DD + lane];
    const float epsB = eps[rowB * DD + lane];
    const float b3m  = b3[lane];
    const float b3p  = b3[64 + lane];
    float za = 0.f, zb = 0.f;

    #pragma unroll 2
    for (int i = 0; i < DD; ++i) {
        // chain-independent preloads & broadcasts, issued first
        float wm[8], wp[8], w1r[8];
        load8(W3T + i * HH + jbase, wm);
        load8(W3T + (DD + i) * HH + jbase, wp);
        load8(W1 + i * HH + jbase, w1r);
        const float ea = __shfl(epsA, i), eb = __shfl(epsB, i);
        const float bm = __shfl(b3m, i), bp = __shfl(b3p, i);

        // (a) select finalized h1 (deg==i); at i==0 this is 0 for every lane
        float ma = 0.f, mb = 0.f;
        #pragma unroll
        for (int u = 0; u < 8; ++u) {
            ma = (deg[u] == i) ? p1a[u] : ma;
            mb = (deg[u] == i) ? p1b[u] : mb;
        }
        ma = fmaxf(ma, 0.f);
        mb = fmaxf(mb, 0.f);

        const int base = (i == 0) ? 0 : (i - 1);
        #pragma unroll
        for (int t = 0; t < 8; ++t) {
            const int k = base + 63 * t;
            const float ha = __shfl(ma, k >> 3);
            const float hb = __shfl(mb, k >> 3);
            float w[8]; load8(W2 + k * HH + jbase, w);
            #pragma unroll
            for (int u = 0; u < 8; ++u) {
                p2a[u] = fmaf(ha, w[u], p2a[u]);
                p2b[u] = fmaf(hb, w[u], p2b[u]);
            }
        }
        {   // t = 8: valid only for i in [1,8]; zero multiplier otherwise
            const int k  = base + 504;
            const int kc = (k < HH) ? k : (HH - 8);
            const float v = (k < HH) ? 1.f : 0.f;
            const float ha = v * __shfl(ma, kc >> 3);
            const float hb = v * __shfl(mb, kc >> 3);
            float w[8]; load8(W2 + kc * HH + jbase, w);
            #pragma unroll
            for (int u = 0; u < 8; ++u) {
                p2a[u] = fmaf(ha, w[u], p2a[u]);
                p2b[u] = fmaf(hb, w[u], p2b[u]);
            }
        }

        // (b) capture h2 for deg==i
        #pragma unroll
        for (int u = 0; u < 8; ++u) {
            if (deg[u] == i) {
                h2a[u] = fmaxf(p2a[u], 0.f);
                h2b[u] = fmaxf(p2b[u], 0.f);
            }
        }

        // (c) output columns i and D+i, both rows, interleaved butterflies
        float m0 = 0.f, q0 = 0.f, m1 = 0.f, q1 = 0.f;
        #pragma unroll
        for (int u = 0; u < 8; ++u) {
            m0 = fmaf(h2a[u], wm[u], m0);
            q0 = fmaf(h2a[u], wp[u], q0);
            m1 = fmaf(h2b[u], wm[u], m1);
            q1 = fmaf(h2b[u], wp[u], q1);
        }
        #pragma unroll
        for (int off = 32; off > 0; off >>= 1) {
            m0 += __shfl_xor(m0, off);
            q0 += __shfl_xor(q0, off);
            m1 += __shfl_xor(m1, off);
            q1 += __shfl_xor(q1, off);
        }
        const float spA = fast_softplus(q0 + bp);
        const float spB = fast_softplus(q1 + bp);
        const float ziA = fmaf(spA, ea, m0 + bm);
        const float ziB = fmaf(spB, eb, m1 + bm);
        if (lane == i) { za = ziA; zb = ziB; }

        // (d) pre1 += z_i * W1[i, :]
        #pragma unroll
        for (int u = 0; u < 8; ++u) {
            p1a[u] = fmaf(ziA, w1r[u], p1a[u]);
            p1b[u] = fmaf(ziB, w1r[u], p1b[u]);
        }
    }

    out[rowA * DD + lane] = za;
    out[rowB * DD + lane] = zb;
}

extern "C" void kernel_launch(void* const* d_in, const int* in_sizes, int n_in,
                              void* d_out, int out_size, void* d_ws, size_t ws_size,
                              hipStream_t stream) {
    const float* ctx = (const float*)d_in[0];
    const float* eps = (const float*)d_in[1];
    const float* W1  = (const float*)d_in[2];
    const float* b1  = (const float*)d_in[3];
    const float* W2  = (const float*)d_in[4];
    const float* b2  = (const float*)d_in[5];
    const float* W3  = (const float*)d_in[6];
    const float* b3  = (const float*)d_in[7];
    float* W3T = (float*)d_ws;   // 2D*H floats = 256 KiB

    transpose_w3<<<(2 * DD * HH) / 256, 256, 0, stream>>>(W3, W3T);
    made_sample<<<BATCH / 8, 256, 0, stream>>>(ctx, eps, W1, b1, W2, b2, b3, W3T,
                                               (float*)d_out);
}

// Round 4
// 202.941 us; speedup vs baseline: 1.5251x; 1.3885x over previous
//
#include <hip/hip_runtime.h>
#include <math.h>

#define DD 64
#define CC 128
#define HH 512
#define BATCH 4096

// Transpose W3 (H, 2D) -> W3T (2D, H) in d_ws.
__global__ void transpose_w3(const float* __restrict__ W3, float* __restrict__ W3T) {
    int idx = blockIdx.x * blockDim.x + threadIdx.x;
    int c = idx >> 9;
    int j = idx & 511;
    W3T[idx] = W3[j * (2 * DD) + c];
}

__device__ __forceinline__ void load8s(const float* __restrict__ p, float* r) {
    float4 a = *(const float4*)(p);
    float4 b = *(const float4*)(p + 4);
    r[0] = a.x; r[1] = a.y; r[2] = a.z; r[3] = a.w;
    r[4] = b.x; r[5] = b.y; r[6] = b.z; r[7] = b.w;
}

__device__ __forceinline__ float fast_softplus(float x) {
    float t = exp2f(-fabsf(x) * 1.44269504f);
    return fmaxf(x, 0.f) + 0.69314718f * log2f(1.f + t);
}

// wave-uniform broadcast via v_readlane (no DS unit)
__device__ __forceinline__ float bcast(float x, int l) {
    return __int_as_float(__builtin_amdgcn_readlane(__float_as_int(x), l));
}

// canonical GCN wave64 sum via DPP (pure VALU): total lands in lane 63
#define DPP_ADD(x, ctrl, rm)                                                          \
    x += __int_as_float(__builtin_amdgcn_update_dpp(0, __float_as_int(x), ctrl, rm, 0xf, true))
__device__ __forceinline__ float wave_allsum(float x) {
    DPP_ADD(x, 0x111, 0xf);  // row_shr:1
    DPP_ADD(x, 0x112, 0xf);  // row_shr:2
    DPP_ADD(x, 0x114, 0xf);  // row_shr:4
    DPP_ADD(x, 0x118, 0xf);  // row_shr:8
    DPP_ADD(x, 0x142, 0xa);  // row_bcast:15 -> rows 1,3
    DPP_ADD(x, 0x143, 0xc);  // row_bcast:31 -> rows 2,3
    return bcast(x, 63);
}

typedef const __attribute__((address_space(1))) void* as1_cptr;
typedef __attribute__((address_space(3))) void* as3_ptr;
__device__ __forceinline__ void glds16(const float* g, float* l) {
    // lane's 16B from g+lane*16 -> ldsbase + lane*16 (wave-uniform lds base)
    __builtin_amdgcn_global_load_lds((as1_cptr)g, (as3_ptr)l, 16, 0, 0);
}

// One block per CU: 4 waves x 4 rows = 16 batch rows. Lane l owns units 8l..8l+7.
// Per step, the 12 weight rows (9 W2 rank-rows + 2 W3T cols + 1 W1 row, 24 KB)
// are staged once into LDS (double-buffered, async) and shared by all 4 waves.
// Broadcasts use v_readlane; reductions use DPP (pure VALU).
//
// t=8 tail row: k = (i-1)+504 is a VALID W2 row whenever k < 512 (i in [1,8],
// rows 504..511). Clamp ONLY k >= 512 (R2 bug: clamped k>504, corrupting i=2..8).
// For any k in [504,512) the broadcast lane k>>3 == 63.
__global__ __launch_bounds__(256, 1) void made_sample(
    const float* __restrict__ ctx,   // (B, C)
    const float* __restrict__ eps,   // (B, D)
    const float* __restrict__ W1,    // (D+C, H)
    const float* __restrict__ b1,    // (H)
    const float* __restrict__ W2,    // (H, H)
    const float* __restrict__ b2,    // (H)
    const float* __restrict__ b3,    // (2D)
    const float* __restrict__ W3T,   // (2D, H)
    float* __restrict__ out)         // (B, D)
{
    const int lane  = threadIdx.x & 63;
    const int w     = threadIdx.x >> 6;          // wave 0..3
    const int rbase = blockIdx.x * 16 + w * 4;   // 4 batch rows per wave
    const int jbase = 8 * lane;

    __shared__ float sbuf[2][12 * HH];           // 2 x 24 KB

    int deg[8];
    #pragma unroll
    for (int u = 0; u < 8; ++u) deg[u] = (jbase + u) % 63 + 1;

    float p1[4][8], p2[4][8], h2[4][8];
    {
        float t1[8], t2[8];
        load8s(b1 + jbase, t1);
        load8s(b2 + jbase, t2);
        #pragma unroll
        for (int r = 0; r < 4; ++r)
            #pragma unroll
            for (int u = 0; u < 8; ++u) { p1[r][u] = t1[u]; p2[r][u] = t2[u]; h2[r][u] = 0.f; }
    }

    float ca[4], cb[4], ep[4];
    #pragma unroll
    for (int r = 0; r < 4; ++r) {
        ca[r] = ctx[(rbase + r) * CC + lane];
        cb[r] = ctx[(rbase + r) * CC + 64 + lane];
        ep[r] = eps[(rbase + r) * DD + lane];
    }
    const float b3m = b3[lane];
    const float b3p = b3[64 + lane];

    // ---- staging helpers ----
    // ctx chunk ch: W1 rows DD+8ch .. DD+8ch+7 into slots 0..7
    auto stage_ctx = [&](int ch, float* buf) {
        #pragma unroll
        for (int q2 = 0; q2 < 2; ++q2) {
            const int q = 2 * w + q2;
            const float* src = W1 + (DD + 8 * ch + q) * HH;
            glds16(src + lane * 4, buf + q * HH);
            glds16(src + 256 + lane * 4, buf + q * HH + 256);
        }
    };
    // main step `in`: W2 rows base+63t (t=0..8; only k>=512 clamped) slots 0..8;
    // W3T rows in, 64+in -> slots 9,10; W1 row in -> slot 11.
    auto stage_step = [&](int in, float* buf) {
        const int basen = (in == 0) ? 0 : (in - 1);
        #pragma unroll
        for (int rr = 0; rr < 3; ++rr) {
            const int r = w + 4 * rr;
            const float* src;
            if (r < 9) {
                int k = basen + 63 * r;
                if (k >= HH) k = HH - 8;    // only truly-OOB rows (mult is zeroed)
                src = W2 + k * HH;
            } else if (r == 9) {
                src = W3T + in * HH;
            } else if (r == 10) {
                src = W3T + (DD + in) * HH;
            } else {
                src = W1 + in * HH;
            }
            glds16(src + lane * 4, buf + r * HH);
            glds16(src + 256 + lane * 4, buf + r * HH + 256);
        }
    };

    // ---- context init: pre1 += ctx @ W1[D:,:], staged in 16 chunks of 8 rows ----
    stage_ctx(0, sbuf[0]);
    __syncthreads();
    #pragma unroll 1
    for (int ch = 0; ch < 16; ++ch) {
        float* cur = sbuf[ch & 1];
        float* nxt = sbuf[(ch + 1) & 1];
        if (ch < 15) stage_ctx(ch + 1, nxt);
        else         stage_step(0, sbuf[0]);     // (16)&1 == 0: main step 0 parity OK
        #pragma unroll
        for (int q = 0; q < 8; ++q) {
            float wv[8];
            load8s(cur + q * HH + jbase, wv);
            const int c = 8 * ch + q;
            #pragma unroll
            for (int r = 0; r < 4; ++r) {
                const float srcv = (ch < 8) ? ca[r] : cb[r];
                const float cv = bcast(srcv, c & 63);
                #pragma unroll
                for (int u = 0; u < 8; ++u) p1[r][u] = fmaf(cv, wv[u], p1[r][u]);
            }
        }
        __syncthreads();
    }

    float z[4] = {0.f, 0.f, 0.f, 0.f};

    // ---- autoregressive main loop ----
    #pragma unroll 1
    for (int i = 0; i < DD; ++i) {
        float* cur = sbuf[i & 1];
        float* nxt = sbuf[(i + 1) & 1];
        if (i < 63) stage_step(i + 1, nxt);

        // W3/W1 rows for this step (independent of the serial chain; issue early)
        float wm[8], wp[8], w1r[8];
        load8s(cur + 9 * HH + jbase, wm);
        load8s(cur + 10 * HH + jbase, wp);
        load8s(cur + 11 * HH + jbase, w1r);

        // (a) select finalized h1 (deg==i); zero at i==0
        float m[4];
        #pragma unroll
        for (int r = 0; r < 4; ++r) {
            float mv = 0.f;
            #pragma unroll
            for (int u = 0; u < 8; ++u) mv = (deg[u] == i) ? p1[r][u] : mv;
            m[r] = fmaxf(mv, 0.f);
        }

        const int base = (i == 0) ? 0 : (i - 1);
        #pragma unroll
        for (int t = 0; t < 9; ++t) {
            const int k = base + 63 * t;
            float wv[8];
            load8s(cur + t * HH + jbase, wv);
            float ha[4];
            if (t == 8) {
                // valid iff k < 512; bcast lane is 63 for all k in [504,512)
                const float vm = (k < HH) ? 1.f : 0.f;
                #pragma unroll
                for (int r = 0; r < 4; ++r) ha[r] = vm * bcast(m[r], 63);
            } else {
                #pragma unroll
                for (int r = 0; r < 4; ++r) ha[r] = bcast(m[r], k >> 3);
            }
            #pragma unroll
            for (int u = 0; u < 8; ++u)
                #pragma unroll
                for (int r = 0; r < 4; ++r) p2[r][u] = fmaf(ha[r], wv[u], p2[r][u]);
        }

        // (b) capture h2 for deg==i
        #pragma unroll
        for (int r = 0; r < 4; ++r)
            #pragma unroll
            for (int u = 0; u < 8; ++u)
                if (deg[u] == i) h2[r][u] = fmaxf(p2[r][u], 0.f);

        // (c) output columns i and D+i for 4 rows; DPP reductions (pure VALU)
        float macc[4], qacc[4];
        #pragma unroll
        for (int r = 0; r < 4; ++r) {
            float ma = 0.f, qa = 0.f;
            #pragma unroll
            for (int u = 0; u < 8; ++u) {
                ma = fmaf(h2[r][u], wm[u], ma);
                qa = fmaf(h2[r][u], wp[u], qa);
            }
            macc[r] = ma; qacc[r] = qa;
        }
        const float bm = bcast(b3m, i);
        const float bp = bcast(b3p, i);
        #pragma unroll
        for (int r = 0; r < 4; ++r) {
            const float mt = wave_allsum(macc[r]) + bm;
            const float qt = wave_allsum(qacc[r]) + bp;
            const float sp = fast_softplus(qt);
            const float ei = bcast(ep[r], i);
            const float zi = fmaf(sp, ei, mt);
            if (lane == i) z[r] = zi;
            #pragma unroll
            for (int u = 0; u < 8; ++u) p1[r][u] = fmaf(zi, w1r[u], p1[r][u]);
        }

        __syncthreads();
    }

    #pragma unroll
    for (int r = 0; r < 4; ++r) out[(rbase + r) * DD + lane] = z[r];
}

extern "C" void kernel_launch(void* const* d_in, const int* in_sizes, int n_in,
                              void* d_out, int out_size, void* d_ws, size_t ws_size,
                              hipStream_t stream) {
    const float* ctx = (const float*)d_in[0];
    const float* eps = (const float*)d_in[1];
    const float* W1  = (const float*)d_in[2];
    const float* b1  = (const float*)d_in[3];
    const float* W2  = (const float*)d_in[4];
    const float* b2  = (const float*)d_in[5];
    const float* W3  = (const float*)d_in[6];
    const float* b3  = (const float*)d_in[7];
    float* W3T = (float*)d_ws;   // 2D*H floats = 256 KiB

    transpose_w3<<<(2 * DD * HH) / 256, 256, 0, stream>>>(W3, W3T);
    made_sample<<<BATCH / 16, 256, 0, stream>>>(ctx, eps, W1, b1, W2, b2, b3, W3T,
                                                (float*)d_out);
}

// Round 5
// 191.194 us; speedup vs baseline: 1.6188x; 1.0614x over previous
//
#include <hip/hip_runtime.h>
#include <math.h>

#define DD 64
#define CC 128
#define HH 512
#define BATCH 4096

// Transpose W3 (H, 2D) -> W3T (2D, H) in d_ws.
__global__ void transpose_w3(const float* __restrict__ W3, float* __restrict__ W3T) {
    int idx = blockIdx.x * blockDim.x + threadIdx.x;
    int c = idx >> 9;
    int j = idx & 511;
    W3T[idx] = W3[j * (2 * DD) + c];
}

__device__ __forceinline__ float fast_softplus(float x) {
    float t = exp2f(-fabsf(x) * 1.44269504f);
    return fmaxf(x, 0.f) + 0.69314718f * log2f(1.f + t);
}

// wave-uniform broadcast via v_readlane (no DS unit)
__device__ __forceinline__ float bcast(float x, int l) {
    return __int_as_float(__builtin_amdgcn_readlane(__float_as_int(x), l));
}

// canonical GCN wave64 sum via DPP (pure VALU): total lands in lane 63
#define DPP_ADD(x, ctrl, rm)                                                          \
    x += __int_as_float(__builtin_amdgcn_update_dpp(0, __float_as_int(x), ctrl, rm, 0xf, true))
__device__ __forceinline__ float wave_allsum(float x) {
    DPP_ADD(x, 0x111, 0xf);  // row_shr:1
    DPP_ADD(x, 0x112, 0xf);  // row_shr:2
    DPP_ADD(x, 0x114, 0xf);  // row_shr:4
    DPP_ADD(x, 0x118, 0xf);  // row_shr:8
    DPP_ADD(x, 0x142, 0xa);  // row_bcast:15 -> rows 1,3
    DPP_ADD(x, 0x143, 0xc);  // row_bcast:31 -> rows 2,3
    return bcast(x, 63);
}

typedef const __attribute__((address_space(1))) void* as1_cptr;
typedef __attribute__((address_space(3))) void* as3_ptr;
__device__ __forceinline__ void glds16(const float* g, float* l) {
    // lane's 16B from per-lane address g -> ldsbase + lane*16 (dest wave-uniform)
    __builtin_amdgcn_global_load_lds((as1_cptr)g, (as3_ptr)l, 16, 0, 0);
}

// CONFLICT-FREE LAYOUT: a 512-float weight row is stored as two 1KB halves:
//   halfA: elements 8l..8l+3  at slot + 16B*l
//   halfB: elements 8l+4..8l+7 at slot + 1KB + 16B*l
// Staged by two glds16 with per-lane source stride 32B (the two instructions
// cover complementary halves of the same cache lines). LDS reads are then
// canonical 16B/lane ds_read_b128 -> zero bank conflicts.
//
// 8 batch rows per block (4 waves x R=2), 512 blocks -> 2 independent blocks/CU
// (launch_bounds(256,2)); one block's barrier/latency stalls overlap the
// other's compute. Per step the 12 weight rows (9 W2 + 2 W3T + 1 W1, 24 KB)
// are staged once per block into a double buffer.
__global__ __launch_bounds__(256, 2) void made_sample(
    const float* __restrict__ ctx,   // (B, C)
    const float* __restrict__ eps,   // (B, D)
    const float* __restrict__ W1,    // (D+C, H)
    const float* __restrict__ b1,    // (H)
    const float* __restrict__ W2,    // (H, H)
    const float* __restrict__ b2,    // (H)
    const float* __restrict__ b3,    // (2D)
    const float* __restrict__ W3T,   // (2D, H)
    float* __restrict__ out)         // (B, D)
{
    const int lane  = threadIdx.x & 63;
    const int w     = threadIdx.x >> 6;          // wave 0..3
    const int rbase = blockIdx.x * 8 + w * 2;    // 2 batch rows per wave
    const int jbase = 8 * lane;

    __shared__ float sbuf[2][12 * HH];           // 2 x 24 KB

    int deg[8];
    #pragma unroll
    for (int u = 0; u < 8; ++u) deg[u] = (jbase + u) % 63 + 1;

    // split-half LDS read: slot base -> 8 floats for this lane
    auto load8lds = [&](const float* base, float* r) {
        float4 a = *(const float4*)(base + lane * 4);
        float4 b = *(const float4*)(base + 256 + lane * 4);
        r[0] = a.x; r[1] = a.y; r[2] = a.z; r[3] = a.w;
        r[4] = b.x; r[5] = b.y; r[6] = b.z; r[7] = b.w;
    };
    // stage one 512-float row into split-half layout (2 glds16)
    auto stage_row = [&](const float* src, float* dst) {
        glds16(src + lane * 8,     dst);
        glds16(src + lane * 8 + 4, dst + 256);
    };

    float p1[2][8], p2[2][8], h2[2][8];
    {
        #pragma unroll
        for (int u = 0; u < 8; ++u) {
            float t1 = b1[jbase + u];
            float t2 = b2[jbase + u];
            p1[0][u] = t1; p1[1][u] = t1;
            p2[0][u] = t2; p2[1][u] = t2;
            h2[0][u] = 0.f; h2[1][u] = 0.f;
        }
    }

    float ca[2], cb[2], ep[2];
    #pragma unroll
    for (int r = 0; r < 2; ++r) {
        ca[r] = ctx[(rbase + r) * CC + lane];
        cb[r] = ctx[(rbase + r) * CC + 64 + lane];
        ep[r] = eps[(rbase + r) * DD + lane];
    }
    const float b3m = b3[lane];
    const float b3p = b3[64 + lane];

    // ctx chunk ch: W1 rows DD+8ch..DD+8ch+7 -> slots 0..7 (2 rows per wave)
    auto stage_ctx = [&](int ch, float* buf) {
        #pragma unroll
        for (int q2 = 0; q2 < 2; ++q2) {
            const int q = 2 * w + q2;
            stage_row(W1 + (DD + 8 * ch + q) * HH, buf + q * HH);
        }
    };
    // main step `in`: W2 rows base+63t (t=0..8; only k>=512 clamped) slots 0..8;
    // W3T rows in, 64+in -> slots 9,10; W1 row in -> slot 11.
    auto stage_step = [&](int in, float* buf) {
        const int basen = (in == 0) ? 0 : (in - 1);
        #pragma unroll
        for (int rr = 0; rr < 3; ++rr) {
            const int r = w + 4 * rr;
            const float* src;
            if (r < 9) {
                int k = basen + 63 * r;
                if (k >= HH) k = HH - 8;    // only truly-OOB rows (mult is zeroed)
                src = W2 + k * HH;
            } else if (r == 9) {
                src = W3T + in * HH;
            } else if (r == 10) {
                src = W3T + (DD + in) * HH;
            } else {
                src = W1 + in * HH;
            }
            stage_row(src, buf + r * HH);
        }
    };

    // ---- context init: pre1 += ctx @ W1[D:,:], staged in 16 chunks of 8 rows ----
    stage_ctx(0, sbuf[0]);
    __syncthreads();
    #pragma unroll 1
    for (int ch = 0; ch < 16; ++ch) {
        float* cur = sbuf[ch & 1];
        float* nxt = sbuf[(ch + 1) & 1];
        if (ch < 15) stage_ctx(ch + 1, nxt);
        else         stage_step(0, sbuf[0]);     // (16)&1 == 0: main step 0 parity OK
        #pragma unroll
        for (int q = 0; q < 8; ++q) {
            float wv[8];
            load8lds(cur + q * HH, wv);
            const int c = 8 * ch + q;
            #pragma unroll
            for (int r = 0; r < 2; ++r) {
                const float srcv = (ch < 8) ? ca[r] : cb[r];
                const float cv = bcast(srcv, c & 63);
                #pragma unroll
                for (int u = 0; u < 8; ++u) p1[r][u] = fmaf(cv, wv[u], p1[r][u]);
            }
        }
        __syncthreads();
    }

    float z[2] = {0.f, 0.f};

    // ---- autoregressive main loop ----
    #pragma unroll 1
    for (int i = 0; i < DD; ++i) {
        float* cur = sbuf[i & 1];
        float* nxt = sbuf[(i + 1) & 1];
        if (i < 63) stage_step(i + 1, nxt);

        // step-independent preloads (off the serial chain)
        float wm[8], wp[8], w1r[8];
        load8lds(cur + 9 * HH, wm);
        load8lds(cur + 10 * HH, wp);
        load8lds(cur + 11 * HH, w1r);

        // (a) select finalized h1 (deg==i); zero at i==0
        float m[2];
        #pragma unroll
        for (int r = 0; r < 2; ++r) {
            float mv = 0.f;
            #pragma unroll
            for (int u = 0; u < 8; ++u) mv = (deg[u] == i) ? p1[r][u] : mv;
            m[r] = fmaxf(mv, 0.f);
        }

        const int base = (i == 0) ? 0 : (i - 1);
        #pragma unroll
        for (int t = 0; t < 9; ++t) {
            const int k = base + 63 * t;
            float wv[8];
            load8lds(cur + t * HH, wv);
            float ha[2];
            if (t == 8) {
                // valid iff k < 512; bcast lane is 63 for all k in [504,512)
                const float vm = (k < HH) ? 1.f : 0.f;
                #pragma unroll
                for (int r = 0; r < 2; ++r) ha[r] = vm * bcast(m[r], 63);
            } else {
                #pragma unroll
                for (int r = 0; r < 2; ++r) ha[r] = bcast(m[r], k >> 3);
            }
            #pragma unroll
            for (int u = 0; u < 8; ++u)
                #pragma unroll
                for (int r = 0; r < 2; ++r) p2[r][u] = fmaf(ha[r], wv[u], p2[r][u]);
        }

        // (b) capture h2 for deg==i
        #pragma unroll
        for (int r = 0; r < 2; ++r)
            #pragma unroll
            for (int u = 0; u < 8; ++u)
                if (deg[u] == i) h2[r][u] = fmaxf(p2[r][u], 0.f);

        // (c) output columns i and D+i; DPP reductions (pure VALU)
        float macc[2], qacc[2];
        #pragma unroll
        for (int r = 0; r < 2; ++r) {
            float ma = 0.f, qa = 0.f;
            #pragma unroll
            for (int u = 0; u < 8; ++u) {
                ma = fmaf(h2[r][u], wm[u], ma);
                qa = fmaf(h2[r][u], wp[u], qa);
            }
            macc[r] = ma; qacc[r] = qa;
        }
        const float bm = bcast(b3m, i);
        const float bp = bcast(b3p, i);
        #pragma unroll
        for (int r = 0; r < 2; ++r) {
            const float mt = wave_allsum(macc[r]) + bm;
            const float qt = wave_allsum(qacc[r]) + bp;
            const float sp = fast_softplus(qt);
            const float ei = bcast(ep[r], i);
            const float zi = fmaf(sp, ei, mt);
            if (lane == i) z[r] = zi;
            #pragma unroll
            for (int u = 0; u < 8; ++u) p1[r][u] = fmaf(zi, w1r[u], p1[r][u]);
        }

        __syncthreads();
    }

    #pragma unroll
    for (int r = 0; r < 2; ++r) out[(rbase + r) * DD + lane] = z[r];
}

extern "C" void kernel_launch(void* const* d_in, const int* in_sizes, int n_in,
                              void* d_out, int out_size, void* d_ws, size_t ws_size,
                              hipStream_t stream) {
    const float* ctx = (const float*)d_in[0];
    const float* eps = (const float*)d_in[1];
    const float* W1  = (const float*)d_in[2];
    const float* b1  = (const float*)d_in[3];
    const float* W2  = (const float*)d_in[4];
    const float* b2  = (const float*)d_in[5];
    const float* W3  = (const float*)d_in[6];
    const float* b3  = (const float*)d_in[7];
    float* W3T = (float*)d_ws;   // 2D*H floats = 256 KiB

    transpose_w3<<<(2 * DD * HH) / 256, 256, 0, stream>>>(W3, W3T);
    made_sample<<<BATCH / 8, 256, 0, stream>>>(ctx, eps, W1, b1, W2, b2, b3, W3T,
                                               (float*)d_out);
}

// Round 6
// 184.657 us; speedup vs baseline: 1.6761x; 1.0354x over previous
//
#include <hip/hip_runtime.h>
#include <math.h>

#define DD 64
#define CC 128
#define HH 512
#define BATCH 4096

typedef __attribute__((ext_vector_type(2))) float f32x2;

__device__ __forceinline__ f32x2 splat2(float x) { f32x2 v; v[0] = x; v[1] = x; return v; }

__device__ __forceinline__ float fast_softplus(float x) {
    float t = exp2f(-fabsf(x) * 1.44269504f);
    return fmaxf(x, 0.f) + 0.69314718f * log2f(1.f + t);
}

// wave-uniform broadcast via v_readlane (no DS unit)
__device__ __forceinline__ float bcast(float x, int l) {
    return __int_as_float(__builtin_amdgcn_readlane(__float_as_int(x), l));
}

typedef const __attribute__((address_space(1))) void* as1_cptr;
typedef __attribute__((address_space(3))) void* as3_ptr;
__device__ __forceinline__ void glds16(const float* g, float* l) {
    // 16B from per-lane address g -> ldsbase + lane*16 (dest wave-uniform)
    __builtin_amdgcn_global_load_lds((as1_cptr)g, (as3_ptr)l, 16, 0, 0);
}

// Single kernel. One block = 4 waves x R=2 rows = 8 batch rows; grid 512 -> 2 blocks/CU.
// Lane l owns hidden units 8l..8l+7 (deg = (j%63)+1), split-half LDS layout
// (elements 8l..8l+3 at +16B*l, 8l+4..8l+7 at +1KB+16B*l) -> conflict-free b128.
//
// NEW vs R5: no W3 transpose / no DPP reductions. Lane c carries, per batch row,
// acc = {mean col c, prescale col 64+c} accumulated incrementally: when unit k
// finalizes at step deg(k), every lane adds h2[k]*{W3[k,c],W3[k,64+c]} from a
// coalesced direct-global read of W3 row k (L2-resident, 256KB total). At step i
// column i's totals live wholly in lane i -> z_i is a single readlane.
// Mask-free: not-yet-final units contribute 0 (h2new select), so acc at step i
// contains exactly the deg<=i terms that column i's M3 mask allows.
__global__ __launch_bounds__(256, 2) void made_sample(
    const float* __restrict__ ctx,   // (B, C)
    const float* __restrict__ eps,   // (B, D)
    const float* __restrict__ W1,    // (D+C, H)
    const float* __restrict__ b1,    // (H)
    const float* __restrict__ W2,    // (H, H)
    const float* __restrict__ b2,    // (H)
    const float* __restrict__ W3,    // (H, 2D)  used directly, no transpose
    const float* __restrict__ b3,    // (2D)
    float* __restrict__ out)         // (B, D)
{
    const int lane  = threadIdx.x & 63;
    const int w     = threadIdx.x >> 6;          // wave 0..3
    const int rbase = blockIdx.x * 8 + w * 2;    // 2 batch rows per wave
    const int jbase = 8 * lane;

    __shared__ float sbuf[2][10 * HH];           // 2 x 20 KB (slots: 9 W2 + 1 W1)

    int deg[8];
    #pragma unroll
    for (int u = 0; u < 8; ++u) deg[u] = (jbase + u) % 63 + 1;

    // split-half LDS read: slot base -> 4 f32x2 (8 floats) for this lane
    auto load8v = [&](const float* base_, f32x2* r_) {
        float4 a = *(const float4*)(base_ + lane * 4);
        float4 b = *(const float4*)(base_ + 256 + lane * 4);
        r_[0][0] = a.x; r_[0][1] = a.y; r_[1][0] = a.z; r_[1][1] = a.w;
        r_[2][0] = b.x; r_[2][1] = b.y; r_[3][0] = b.z; r_[3][1] = b.w;
    };
    // stage one 512-float row into split-half layout (2 glds16)
    auto stage_row = [&](const float* src, float* dst) {
        glds16(src + lane * 8,     dst);
        glds16(src + lane * 8 + 4, dst + 256);
    };

    f32x2 p1[2][4], p2[2][4], acc[2];
    #pragma unroll
    for (int j = 0; j < 4; ++j) {
        f32x2 t1, t2;
        t1[0] = b1[jbase + 2 * j]; t1[1] = b1[jbase + 2 * j + 1];
        t2[0] = b2[jbase + 2 * j]; t2[1] = b2[jbase + 2 * j + 1];
        p1[0][j] = t1; p1[1][j] = t1;
        p2[0][j] = t2; p2[1][j] = t2;
    }
    acc[0] = splat2(0.f);
    acc[1] = splat2(0.f);

    float ca[2], cb[2], ep[2];
    #pragma unroll
    for (int r = 0; r < 2; ++r) {
        ca[r] = ctx[(rbase + r) * CC + lane];
        cb[r] = ctx[(rbase + r) * CC + 64 + lane];
        ep[r] = eps[(rbase + r) * DD + lane];
    }
    const float b3m = b3[lane];        // bias for mean col `lane`
    const float b3p = b3[64 + lane];   // bias for prescale col `lane`

    // ctx chunk ch: W1 rows DD+8ch..DD+8ch+7 -> slots 0..7 (2 rows per wave)
    auto stage_ctx = [&](int ch, float* buf) {
        #pragma unroll
        for (int q2 = 0; q2 < 2; ++q2) {
            const int q = 2 * w + q2;
            stage_row(W1 + (DD + 8 * ch + q) * HH, buf + q * HH);
        }
    };
    // main step `in`: W2 rows basen+63t (t=0..8; k>=512 clamped, mult zeroed)
    // -> slots 0..8; W1 row `in` -> slot 9. Wave w stages rows {w, 4+w, 8+w<=9}.
    auto stage_step = [&](int in, float* buf) {
        const int basen = (in == 0) ? 0 : (in - 1);
        #pragma unroll
        for (int rr = 0; rr < 3; ++rr) {
            const int r = w + 4 * rr;
            if (r <= 9) {
                const float* src;
                if (r < 9) {
                    int k = basen + 63 * r;
                    if (k >= HH) k = HH - 8;
                    src = W2 + k * HH;
                } else {
                    src = W1 + in * HH;
                }
                stage_row(src, buf + r * HH);
            }
        }
    };

    // ---- context init: pre1 += ctx @ W1[D:,:], 16 chunks of 8 rows ----
    stage_ctx(0, sbuf[0]);
    __syncthreads();
    #pragma unroll 1
    for (int ch = 0; ch < 16; ++ch) {
        float* cur = sbuf[ch & 1];
        float* nxt = sbuf[(ch + 1) & 1];
        if (ch < 15) stage_ctx(ch + 1, nxt);
        else         stage_step(0, sbuf[0]);     // (16)&1==0: step-0 parity OK
        #pragma unroll
        for (int q = 0; q < 8; ++q) {
            f32x2 wv[4];
            load8v(cur + q * HH, wv);
            const int c = 8 * ch + q;
            #pragma unroll
            for (int r = 0; r < 2; ++r) {
                const float cv = bcast((ch < 8) ? ca[r] : cb[r], c & 63);
                const f32x2 cv2 = splat2(cv);
                #pragma unroll
                for (int j = 0; j < 4; ++j) p1[r][j] += cv2 * wv[j];
            }
        }
        __syncthreads();
    }

    float z[2] = {0.f, 0.f};

    // ---- autoregressive main loop ----
    #pragma unroll 1
    for (int i = 0; i < DD; ++i) {
        float* cur = sbuf[i & 1];
        float* nxt = sbuf[(i + 1) & 1];
        if (i < 63) stage_step(i + 1, nxt);

        const int base = (i == 0) ? 0 : (i - 1);

        // W3 rows for the units finalizing this step — direct global, coalesced,
        // depends only on i: issue at top, consumed after the rank update.
        f32x2 w3v[9];
        #pragma unroll
        for (int t = 0; t < 9; ++t) {
            const int k  = base + 63 * t;
            const int ks = (k < HH) ? k : (HH - 1);
            w3v[t][0] = W3[ks * (2 * DD) + lane];
            w3v[t][1] = W3[ks * (2 * DD) + 64 + lane];
        }

        // (a) select finalized h1 (deg==i); zero at i==0
        float m[2];
        #pragma unroll
        for (int r = 0; r < 2; ++r) {
            float mv = 0.f;
            #pragma unroll
            for (int u = 0; u < 8; ++u)
                mv = (deg[u] == i) ? p1[r][u >> 1][u & 1] : mv;
            m[r] = fmaxf(mv, 0.f);
        }

        // (b) rank-9 update of pre2 from LDS W2 rows
        #pragma unroll
        for (int t = 0; t < 9; ++t) {
            const int k = base + 63 * t;
            f32x2 wv[4];
            load8v(cur + t * HH, wv);
            float h0, h1v;
            if (t == 8) {
                const float vm = (k < HH) ? 1.f : 0.f;   // bcast lane 63 for k in [504,512)
                h0  = vm * bcast(m[0], 63);
                h1v = vm * bcast(m[1], 63);
            } else {
                h0  = bcast(m[0], k >> 3);
                h1v = bcast(m[1], k >> 3);
            }
            const f32x2 h0v = splat2(h0), h1vv = splat2(h1v);
            #pragma unroll
            for (int j = 0; j < 4; ++j) {
                p2[0][j] += h0v  * wv[j];
                p2[1][j] += h1vv * wv[j];
            }
        }

        // (c) capture newly-final h2 (deg==i), one scalar per lane per row
        float hn[2];
        #pragma unroll
        for (int r = 0; r < 2; ++r) {
            float hv = 0.f;
            #pragma unroll
            for (int u = 0; u < 8; ++u)
                hv = (deg[u] == i) ? p2[r][u >> 1][u & 1] : hv;
            hn[r] = fmaxf(hv, 0.f);
        }

        // (d) incremental output accumulation: acc += h2[k_t] * {W3[k_t,c], W3[k_t,64+c]}
        #pragma unroll
        for (int t = 0; t < 9; ++t) {
            const int k = base + 63 * t;
            float h0, h1v;
            if (t == 8) {
                const float vm = (k < HH) ? 1.f : 0.f;
                h0  = vm * bcast(hn[0], 63);
                h1v = vm * bcast(hn[1], 63);
            } else {
                h0  = bcast(hn[0], k >> 3);
                h1v = bcast(hn[1], k >> 3);
            }
            acc[0] += splat2(h0)  * w3v[t];
            acc[1] += splat2(h1v) * w3v[t];
        }

        // (e) z_i: column i's totals live in lane i; every lane computes its own
        // candidate (parallel), one readlane extracts the real one.
        f32x2 w1v[4];
        load8v(cur + 9 * HH, w1v);
        #pragma unroll
        for (int r = 0; r < 2; ++r) {
            const float am = acc[r][0] + b3m;
            const float ap = acc[r][1] + b3p;
            const float sp = fast_softplus(ap);
            const float zc = fmaf(sp, ep[r], am);
            const float zi = bcast(zc, i);
            if (lane == i) z[r] = zi;
            const f32x2 zi2 = splat2(zi);
            #pragma unroll
            for (int j = 0; j < 4; ++j) p1[r][j] += zi2 * w1v[j];
        }

        __syncthreads();
    }

    #pragma unroll
    for (int r = 0; r < 2; ++r) out[(rbase + r) * DD + lane] = z[r];
}

extern "C" void kernel_launch(void* const* d_in, const int* in_sizes, int n_in,
                              void* d_out, int out_size, void* d_ws, size_t ws_size,
                              hipStream_t stream) {
    const float* ctx = (const float*)d_in[0];
    const float* eps = (const float*)d_in[1];
    const float* W1  = (const float*)d_in[2];
    const float* b1  = (const float*)d_in[3];
    const float* W2  = (const float*)d_in[4];
    const float* b2  = (const float*)d_in[5];
    const float* W3  = (const float*)d_in[6];
    const float* b3  = (const float*)d_in[7];
    (void)d_ws; (void)ws_size; (void)in_sizes; (void)n_in; (void)out_size;

    made_sample<<<BATCH / 8, 256, 0, stream>>>(ctx, eps, W1, b1, W2, b2, W3, b3,
                                               (float*)d_out);
}